// Round 12
// baseline (16431.772 us; speedup 1.0000x reference)
//
#include <hip/hip_runtime.h>

#define T_ 1024
#define B_ 32
#define D_ 512
#define FF_ 2048
#define TB_ 32768   // T_*B_

typedef short bf16x8 __attribute__((ext_vector_type(8)));
typedef float f32x4 __attribute__((ext_vector_type(4)));

static __device__ __forceinline__ unsigned int pack2bf(float a, float b){
  union { __bf16 h[2]; unsigned int u; } z;
  z.h[0] = (__bf16)a; z.h[1] = (__bf16)b; return z.u;
}
static __device__ __forceinline__ float sigm(float x){ return 1.f/(1.f+__expf(-x)); }
static __device__ __forceinline__ float tanh_(float x){ return 1.f - 2.f/(1.f+__expf(2.f*x)); }

// first[] may be uint8 (numpy bool) or int32; detected at runtime.
static __device__ __forceinline__ bool firstval(const void* p, int mode, int idx){
  return mode ? (((const int*)p)[idx] != 0) : (((const unsigned char*)p)[idx] != 0);
}

// ---------------------------------------------------------------- detect bool dtype
__global__ void detect_first_kernel(const unsigned char* __restrict__ p, unsigned int* __restrict__ mode){
  __shared__ int found;
  if (threadIdx.x == 0) found = 0;
  __syncthreads();
  int f = 0;
  for (int i = threadIdx.x; i < TB_; i += 256) if ((i & 3) != 0 && p[i] != 0) f = 1;
  if (f) atomicAdd(&found, 1);
  __syncthreads();
  if (threadIdx.x == 0) *mode = (found == 0) ? 1u : 0u;   // 1 => int32, 0 => uint8
}

// ---------------------------------------------------------------- weight conversion
__global__ void convert_w_kernel(const float* __restrict__ Wih, const float* __restrict__ Whh,
                                 const float* __restrict__ m0w, const float* __restrict__ m1w,
                                 const float* __restrict__ aw0, const float* __restrict__ aw1,
                                 __bf16* __restrict__ Wihb, __bf16* __restrict__ Whhb,
                                 __bf16* __restrict__ m0b,  __bf16* __restrict__ m1b,
                                 __bf16* __restrict__ awT0, __bf16* __restrict__ awT1){
  int bid = blockIdx.x;
  if (bid < 4096) {
    int ai = bid >> 10;
    size_t off = (size_t)(bid & 1023) * 1024 + threadIdx.x * 4;
    const float* src = (ai==0)?Wih:(ai==1)?Whh:(ai==2)?m0w:m1w;
    __bf16* dst = (ai==0)?Wihb:(ai==1)?Whhb:(ai==2)?m0b:m1b;
    float4 v = *(const float4*)(src + off);
    union { __bf16 h[4]; uint2 u; } z;
    z.h[0]=(__bf16)v.x; z.h[1]=(__bf16)v.y; z.h[2]=(__bf16)v.z; z.h[3]=(__bf16)v.w;
    *(uint2*)(void*)(dst + off) = z.u;
  } else {
    int e = (bid - 4096) * 256 + threadIdx.x;      // 0..65535
    if (e < 32768) { int k = e >> 6, j = e & 63;  awT0[e] = (__bf16)aw0[j*512 + k]; }
    else { int e2 = e - 32768; int j = e2 >> 9, d = e2 & 511; awT1[e2] = (__bf16)aw1[d*64 + j]; }
  }
}

// ---------------------------------------------------------------- layernorm -> bf16 (full T)
__global__ __launch_bounds__(256) void ln_kernel(const float* __restrict__ x,
                                                 const float* __restrict__ g, const float* __restrict__ b,
                                                 __bf16* __restrict__ xn){
  const int w = threadIdx.x >> 6, l = threadIdx.x & 63;
  const int row = blockIdx.x * 4 + w;
  const float* xr = x + (size_t)row * D_;
  const int e0 = l * 4, e1 = 256 + l * 4;
  float4 v0 = *(const float4*)(xr + e0);
  float4 v1 = *(const float4*)(xr + e1);
  float s  = v0.x+v0.y+v0.z+v0.w + v1.x+v1.y+v1.z+v1.w;
  float s2 = v0.x*v0.x+v0.y*v0.y+v0.z*v0.z+v0.w*v0.w + v1.x*v1.x+v1.y*v1.y+v1.z*v1.z+v1.w*v1.w;
  #pragma unroll
  for (int off = 1; off < 64; off <<= 1) { s += __shfl_xor(s, off); s2 += __shfl_xor(s2, off); }
  float mu = s * (1.f/512.f);
  float var = s2 * (1.f/512.f) - mu*mu;
  float rstd = rsqrtf(var + 1e-5f);
  float4 g0 = *(const float4*)(g + e0), g1 = *(const float4*)(g + e1);
  float4 b0 = *(const float4*)(b + e0), b1 = *(const float4*)(b + e1);
  union { __bf16 h[4]; uint2 u; } o0, o1;
  o0.h[0]=(__bf16)((v0.x-mu)*rstd*g0.x+b0.x); o0.h[1]=(__bf16)((v0.y-mu)*rstd*g0.y+b0.y);
  o0.h[2]=(__bf16)((v0.z-mu)*rstd*g0.z+b0.z); o0.h[3]=(__bf16)((v0.w-mu)*rstd*g0.w+b0.w);
  o1.h[0]=(__bf16)((v1.x-mu)*rstd*g1.x+b1.x); o1.h[1]=(__bf16)((v1.y-mu)*rstd*g1.y+b1.y);
  o1.h[2]=(__bf16)((v1.z-mu)*rstd*g1.z+b1.z); o1.h[3]=(__bf16)((v1.w-mu)*rstd*g1.w+b1.w);
  *(uint2*)(void*)(xn + (size_t)row * D_ + e0) = o0.u;
  *(uint2*)(void*)(xn + (size_t)row * D_ + e1) = o1.u;
}

// ---------------------------------------------------------------- bf16 "BT" GEMM  C[M,N] = A[M,K] @ W[N,K]^T + bias  (r6-proven)
template<int RELU, int BF16OUT>
__global__ __launch_bounds__(256) void gemm_bt(const __bf16* __restrict__ A, const __bf16* __restrict__ W,
                                               const float* __restrict__ bias0,
                                               float* __restrict__ Cf, __bf16* __restrict__ Cb,
                                               int M, int N, int K){
  __shared__ __bf16 As[128*64];
  __shared__ __bf16 Bs[128*64];
  const int tid = threadIdx.x, w = tid >> 6, l = tid & 63;
  const int bm = blockIdx.x, bn = blockIdx.y;
  const int wm = (w >> 1) * 64, wn = (w & 1) * 64;
  const int nk = K >> 6;

  uint4 ra[4], rb[4];
  #pragma unroll
  for (int i = 0; i < 4; ++i) {
    int s = tid + (i << 8); int row = s >> 3; int ks = s & 7;
    ra[i] = *(const uint4*)(void*)(A + (size_t)(bm*128 + row) * K + ks*8);
    rb[i] = *(const uint4*)(void*)(W + (size_t)(bn*128 + row) * K + ks*8);
  }
  f32x4 acc[4][4];
  #pragma unroll
  for (int mt = 0; mt < 4; ++mt)
    #pragma unroll
    for (int nt = 0; nt < 4; ++nt) acc[mt][nt] = (f32x4){0.f,0.f,0.f,0.f};

  for (int kt = 0; kt < nk; ++kt) {
    __syncthreads();
    #pragma unroll
    for (int i = 0; i < 4; ++i) {
      int s = tid + (i << 8); int row = s >> 3; int ks = s & 7;
      int wi = row * 64 + ((ks * 8) ^ ((row & 7) << 3));   // XOR swizzle (elements)
      *(uint4*)(void*)(As + wi) = ra[i];
      *(uint4*)(void*)(Bs + wi) = rb[i];
    }
    __syncthreads();
    if (kt + 1 < nk) {
      #pragma unroll
      for (int i = 0; i < 4; ++i) {
        int s = tid + (i << 8); int row = s >> 3; int ks = s & 7;
        ra[i] = *(const uint4*)(void*)(A + (size_t)(bm*128 + row) * K + (kt+1)*64 + ks*8);
        rb[i] = *(const uint4*)(void*)(W + (size_t)(bn*128 + row) * K + (kt+1)*64 + ks*8);
      }
    }
    #pragma unroll
    for (int kk = 0; kk < 2; ++kk) {
      bf16x8 af[4], bfv[4];
      const int ke = kk * 32 + ((l >> 4) << 3);
      #pragma unroll
      for (int mt = 0; mt < 4; ++mt) {
        int row = wm + mt*16 + (l & 15);
        af[mt] = *(const bf16x8*)(void*)(As + row*64 + (ke ^ ((row & 7) << 3)));
      }
      #pragma unroll
      for (int nt = 0; nt < 4; ++nt) {
        int row = wn + nt*16 + (l & 15);
        bfv[nt] = *(const bf16x8*)(void*)(Bs + row*64 + (ke ^ ((row & 7) << 3)));
      }
      #pragma unroll
      for (int mt = 0; mt < 4; ++mt)
        #pragma unroll
        for (int nt = 0; nt < 4; ++nt)
          acc[mt][nt] = __builtin_amdgcn_mfma_f32_16x16x32_bf16(af[mt], bfv[nt], acc[mt][nt], 0, 0, 0);
    }
  }
  // epilogue: D row = (l>>4)*4+j, col = l&15 (m89-verified layout)
  #pragma unroll
  for (int nt = 0; nt < 4; ++nt) {
    int c = bn*128 + wn + nt*16 + (l & 15);
    float bv = bias0[c];
    #pragma unroll
    for (int mt = 0; mt < 4; ++mt) {
      #pragma unroll
      for (int j = 0; j < 4; ++j) {
        int r = bm*128 + wm + mt*16 + ((l >> 4) << 2) + j;
        float v = acc[mt][nt][j] + bv;
        if (RELU) v = fmaxf(v, 0.f);
        if (BF16OUT) Cb[(size_t)r * N + c] = (__bf16)v;
        else         Cf[(size_t)r * N + c] = v;
      }
    }
  }
}

// ---------------------------------------------------------------- LSTM scan, full T, single launch
// r6-proven 8B self-validating packet exchange (1 LLC hop/step). NEW: the xn@Wih^T
// contribution (no sequential dependency) is computed INSIDE the poll-wait shadow each
// step, from streamed Wih/xn fragments -> the entire pre-GEMM disappears from the
// timeline. Biases (bih+bhh) fold into the cell phase.
__global__ __launch_bounds__(512) void lstm_scan(
    const __bf16* __restrict__ Whh,      // [2048][512] bf16
    const __bf16* __restrict__ Wih,      // [2048][512] bf16
    const __bf16* __restrict__ xnb,      // [TB][512] bf16 (LayerNorm'd x)
    const float*  __restrict__ x,        // residual
    const void*   __restrict__ firstp,
    const float*  __restrict__ h0,
    const float*  __restrict__ c0,
    const float*  __restrict__ bih,
    const float*  __restrict__ bhh,
    __bf16*       __restrict__ ymidb,    // [TB][512] bf16
    unsigned long long* __restrict__ HP, // [2][8192] packets
    const unsigned int* __restrict__ modep,
    float* __restrict__ hout, float* __restrict__ cout){
  const int s = blockIdx.x, tid = threadIdx.x, w = tid >> 6, l = tid & 63;
  const int d0 = s * 32;
  __shared__ __bf16 Hl[32 * 512];      // staged H, stride 512 + XOR swizzle (2-way max)
  __shared__ float  gl[32 * 132];      // gate exchange, stride 132 (2-way max)
  const int mode = (int)*modep;

  // Whh B-fragments resident in VGPRs: wave w owns gate rows rl = w*16 + (l&15)
  const int rl = w*16 + (l & 15);
  const int gr = (rl >> 5) * 512 + d0 + (rl & 31);   // PyTorch gate order i,f,g,o
  bf16x8 wf[16];
  {
    const __bf16* base = Whh + (size_t)gr * 512 + ((l >> 4) << 3);
    #pragma unroll
    for (int kt = 0; kt < 16; ++kt) wf[kt] = *(const bf16x8*)(void*)(base + kt*32);
  }
  const __bf16* wib = Wih + (size_t)gr * 512 + ((l >> 4) << 3);  // streamed per step
  const int b = tid >> 4, dl2 = (tid & 15) * 2;    // producer role: (batch, dim pair)
  const int dg = d0 + dl2;
  const int opid = b * 256 + s * 16 + (tid & 15);  // own packet id

  // bias (bih+bhh) for this thread's 4 gates x 2 dims
  float2 bsum[4];
  #pragma unroll
  for (int gi = 0; gi < 4; ++gi) {
    int idx = gi*512 + dg;
    bsum[gi] = make_float2(bih[idx] + bhh[idx], bih[idx+1] + bhh[idx+1]);
  }

  float cr[2];
  {
    float k0 = firstval(firstp, mode, b) ? 0.f : 1.f;
    float2 c2 = *(const float2*)(c0 + (size_t)b*512 + dg);
    cr[0] = c2.x * k0; cr[1] = c2.y * k0;            // keep(first[0]) pre-multiplied
    float2 h = *(const float2*)(h0 + (size_t)b*512 + dg);
    unsigned long long pkt = (1ULL << 32) | (unsigned long long)pack2bf(h.x*k0, h.y*k0);
    __hip_atomic_store(HP + opid, pkt, __ATOMIC_RELAXED, __HIP_MEMORY_SCOPE_AGENT);
  }

  for (int t = 0; t < T_; ++t) {
    const int rowg = t * 32 + b;
    float2 xv = *(const float2*)(x + (size_t)rowg * 512 + dg);
    const bool f_t1 = (t < T_-1) ? firstval(firstp, mode, rowg + 32) : false;

    // ---- issue poll loads (coalesced: thread tid owns pids {tid + j*512})
    const unsigned want = (unsigned)(t + 1);
    const unsigned long long* Pb = HP + ((size_t)(t & 1) << 13);
    unsigned long long pk[16];
    #pragma unroll
    for (int j = 0; j < 16; ++j)
      pk[j] = __hip_atomic_load(Pb + tid + (j << 9), __ATOMIC_RELAXED, __HIP_MEMORY_SCOPE_AGENT);

    // ---- xn @ Wih^T in the wait shadow (dependency-free; 2 interleaved chains per acc)
    f32x4 a0a = (f32x4){0.f,0.f,0.f,0.f}, a0b = (f32x4){0.f,0.f,0.f,0.f};
    f32x4 a1a = (f32x4){0.f,0.f,0.f,0.f}, a1b = (f32x4){0.f,0.f,0.f,0.f};
    {
      const __bf16* xr0 = xnb + (size_t)(t*32 + (l & 15)) * 512 + ((l >> 4) << 3);
      const __bf16* xr1 = xr0 + 16*512;
      #pragma unroll
      for (int kt = 0; kt < 16; kt += 2) {
        bf16x8 wi0 = *(const bf16x8*)(void*)(wib + kt*32);
        bf16x8 wi1 = *(const bf16x8*)(void*)(wib + (kt+1)*32);
        bf16x8 x00 = *(const bf16x8*)(void*)(xr0 + kt*32);
        bf16x8 x01 = *(const bf16x8*)(void*)(xr0 + (kt+1)*32);
        bf16x8 x10 = *(const bf16x8*)(void*)(xr1 + kt*32);
        bf16x8 x11 = *(const bf16x8*)(void*)(xr1 + (kt+1)*32);
        a0a = __builtin_amdgcn_mfma_f32_16x16x32_bf16(x00, wi0, a0a, 0, 0, 0);
        a0b = __builtin_amdgcn_mfma_f32_16x16x32_bf16(x01, wi1, a0b, 0, 0, 0);
        a1a = __builtin_amdgcn_mfma_f32_16x16x32_bf16(x10, wi0, a1a, 0, 0, 0);
        a1b = __builtin_amdgcn_mfma_f32_16x16x32_bf16(x11, wi1, a1b, 0, 0, 0);
      }
    }

    // ---- spin until all 16 packets carry tag t+1
    while (true) {
      unsigned stale = 0;
      #pragma unroll
      for (int j = 0; j < 16; ++j)
        if ((unsigned)(pk[j] >> 32) != want) stale |= (1u << j);
      if (!stale) break;
      __builtin_amdgcn_s_sleep(1);
      #pragma unroll
      for (int j = 0; j < 16; ++j)
        if (stale & (1u << j))
          pk[j] = __hip_atomic_load(Pb + tid + (j << 9), __ATOMIC_RELAXED, __HIP_MEMORY_SCOPE_AGENT);
    }
    // payloads -> LDS: pid = pb*256 + ps*16 + pi -> row pb, elems ps*32 + pi*2 (swizzled)
    #pragma unroll
    for (int j = 0; j < 16; ++j) {
      int pid = tid + (j << 9);
      int pb = pid >> 8, ps = (pid >> 4) & 15, pi = pid & 15;
      int q = ps*32 + pi*2;
      *(unsigned int*)(void*)(Hl + pb*512 + (q ^ ((pb & 7) << 3))) = (unsigned)pk[j];
    }
    __syncthreads();

    // ---- h @ Whh^T accumulated on top of the xn part
    #pragma unroll
    for (int kt = 0; kt < 16; kt += 2) {
      int ke0 = kt*32 + ((l >> 4) << 3), ke1 = (kt+1)*32 + ((l >> 4) << 3);
      int r0 = (l & 15), r1 = 16 + (l & 15);
      bf16x8 h00 = *(const bf16x8*)(void*)(Hl + r0*512 + (ke0 ^ ((r0 & 7) << 3)));
      bf16x8 h01 = *(const bf16x8*)(void*)(Hl + r0*512 + (ke1 ^ ((r0 & 7) << 3)));
      bf16x8 h10 = *(const bf16x8*)(void*)(Hl + r1*512 + (ke0 ^ ((r1 & 7) << 3)));
      bf16x8 h11 = *(const bf16x8*)(void*)(Hl + r1*512 + (ke1 ^ ((r1 & 7) << 3)));
      a0a = __builtin_amdgcn_mfma_f32_16x16x32_bf16(h00, wf[kt],   a0a, 0, 0, 0);
      a0b = __builtin_amdgcn_mfma_f32_16x16x32_bf16(h01, wf[kt+1], a0b, 0, 0, 0);
      a1a = __builtin_amdgcn_mfma_f32_16x16x32_bf16(h10, wf[kt],   a1a, 0, 0, 0);
      a1b = __builtin_amdgcn_mfma_f32_16x16x32_bf16(h11, wf[kt+1], a1b, 0, 0, 0);
    }
    f32x4 acc0 = a0a + a0b, acc1 = a1a + a1b;
    // ---- gate exchange through LDS (stride 132: 2-way max both sides)
    {
      int col = w*16 + (l & 15);
      #pragma unroll
      for (int j = 0; j < 4; ++j) {
        gl[(((l >> 4) << 2) + j) * 132 + col]        = acc0[j];
        gl[((16 + ((l >> 4) << 2) + j)) * 132 + col] = acc1[j];
      }
    }
    __syncthreads();

    // ---- cell update for (b, dg), (b, dg+1); cr pre-multiplied by keep(first[t])
    float2 gv[4];
    #pragma unroll
    for (int gi = 0; gi < 4; ++gi) gv[gi] = *(const float2*)(gl + b*132 + gi*32 + dl2);
    const float keep1 = f_t1 ? 0.f : 1.f;
    float hh[2], cc[2];
    #pragma unroll
    for (int p = 0; p < 2; ++p) {
      float gi_ = (p ? gv[0].y : gv[0].x) + (p ? bsum[0].y : bsum[0].x);
      float gf_ = (p ? gv[1].y : gv[1].x) + (p ? bsum[1].y : bsum[1].x);
      float gg_ = (p ? gv[2].y : gv[2].x) + (p ? bsum[2].y : bsum[2].x);
      float go_ = (p ? gv[3].y : gv[3].x) + (p ? bsum[3].y : bsum[3].x);
      float cn = sigm(gf_) * cr[p] + sigm(gi_) * tanh_(gg_);
      float h  = sigm(go_) * tanh_(cn);
      cc[p] = cn; hh[p] = h;
    }
    cr[0] = cc[0] * keep1; cr[1] = cc[1] * keep1;
    float2 yv = { hh[0] + xv.x, hh[1] + xv.y };
    if (t < T_-1) {
      // publish own packet (tag t+2) -- the payload rides with the tag (release)
      unsigned long long pkt = (((unsigned long long)(unsigned)(t + 2)) << 32)
                             | (unsigned long long)pack2bf(hh[0]*keep1, hh[1]*keep1);
      __hip_atomic_store(HP + (((size_t)((t+1) & 1)) << 13) + opid, pkt,
                         __ATOMIC_RELAXED, __HIP_MEMORY_SCOPE_AGENT);
    } else {
      *(float2*)(hout + (size_t)b*512 + dg) = make_float2(hh[0], hh[1]);
      *(float2*)(cout + (size_t)b*512 + dg) = make_float2(cc[0], cc[1]);
    }
    // no end-of-iter barrier: next iteration's post-stage __syncthreads orders LDS reuse.
    *(unsigned int*)(void*)(ymidb + (size_t)rowg * 512 + dg) = pack2bf(yv.x, yv.y);
  }
}

// ---------------------------------------------------------------- fused adapter + final residual (in-place on y2)
__global__ __launch_bounds__(256) void adapter_out_kernel(
    float* __restrict__ y2,              // [TB][512] in/out (lives in d_out)
    const __bf16* __restrict__ ymidb,    // [TB][512]
    const __bf16* __restrict__ awT0,     // [512][64] = aw0^T
    const __bf16* __restrict__ awT1,     // [64][512] = aw1^T
    const float* __restrict__ ab0, const float* __restrict__ ab1){
  __shared__ float zl[16 * 64];
  const int w = threadIdx.x >> 6, l = threadIdx.x & 63;
  const int r0 = blockIdx.x * 16;
  const float bz = ab0[l];
  #pragma unroll
  for (int rr = 0; rr < 4; ++rr) {
    int rowl = w*4 + rr;
    const float* yr = y2 + (size_t)(r0 + rowl) * 512;
    float acc = bz;
    #pragma unroll 4
    for (int k = 0; k < 512; ++k) acc += yr[k] * (float)awT0[k*64 + l];
    zl[rowl*64 + l] = fmaxf(acc, 0.f);
  }
  __syncthreads();
  #pragma unroll
  for (int rr = 0; rr < 4; ++rr) {
    int rowl = w*4 + rr; int row = r0 + rowl;
    const float* yr = y2  + (size_t)row * 512;
    const __bf16* mr = ymidb + (size_t)row * 512;
    #pragma unroll
    for (int dd = 0; dd < 8; ++dd) {
      int d = dd*64 + l;
      float acc = ab1[d] + yr[d] + (float)mr[d];
      #pragma unroll 4
      for (int j = 0; j < 64; ++j) acc += zl[rowl*64 + j] * (float)awT1[j*512 + d];
      y2[(size_t)row * 512 + d] = acc;
    }
  }
}

// ---------------------------------------------------------------- launch
extern "C" void kernel_launch(void* const* d_in, const int* in_sizes, int n_in,
                              void* d_out, int out_size, void* d_ws, size_t ws_size,
                              hipStream_t stream){
  (void)in_sizes; (void)n_in; (void)out_size; (void)ws_size;
  const float* x    = (const float*)d_in[0];
  const void*  first=               d_in[1];
  const float* h0   = (const float*)d_in[2];
  const float* c0   = (const float*)d_in[3];
  const float* ln_g = (const float*)d_in[4];
  const float* ln_b = (const float*)d_in[5];
  const float* Wih  = (const float*)d_in[6];
  const float* Whh  = (const float*)d_in[7];
  const float* bih  = (const float*)d_in[8];
  const float* bhh  = (const float*)d_in[9];
  const float* m0w  = (const float*)d_in[10];
  const float* m0b  = (const float*)d_in[11];
  const float* m1w  = (const float*)d_in[12];
  const float* m1b  = (const float*)d_in[13];
  const float* aw0  = (const float*)d_in[14];
  const float* ab0  = (const float*)d_in[15];
  const float* aw1  = (const float*)d_in[16];
  const float* ab1  = (const float*)d_in[17];

  // workspace layout — ~109.3 MB (ws >= 126 MB proven by Plan-A runs in r10/r11)
  // [0, 64 MB):  xnbf (32 MB, dead after scan), then a1 (64 MB) for the FFN passes
  char* ws = (char*)d_ws;
  __bf16* xnbf  = (__bf16*)(ws + 0LL);
  __bf16* a1    = (__bf16*)(ws + 0LL);             // alias (disjoint lifetime)
  __bf16* ymidb = (__bf16*)(ws + 67108864LL);      // 32 MB
  __bf16* wihb  = (__bf16*)(ws + 100663296LL);     // 2 MB
  __bf16* whhb  = (__bf16*)(ws + 102760448LL);     // 2 MB
  __bf16* m0bf  = (__bf16*)(ws + 104857600LL);     // 2 MB
  __bf16* m1bf  = (__bf16*)(ws + 106954752LL);     // 2 MB
  __bf16* awT0  = (__bf16*)(ws + 109051904LL);     // 64 KB
  __bf16* awT1  = (__bf16*)(ws + 109117440LL);     // 64 KB
  unsigned long long* HP = (unsigned long long*)(ws + 109182976LL);  // 128 KB
  unsigned int* mode = (unsigned int*)(ws + 109314048LL);

  float* out  = (float*)d_out;
  float* hout = out + (size_t)TB_ * D_;
  float* cout = hout + B_ * D_;

  hipMemsetAsync(HP, 0, 131072, stream);           // kill cross-replay stale tags
  detect_first_kernel<<<1, 256, 0, stream>>>((const unsigned char*)first, mode);
  convert_w_kernel<<<4352, 256, 0, stream>>>(Wih, Whh, m0w, m1w, aw0, aw1,
                                             wihb, whhb, m0bf, m1bf, awT0, awT1);
  ln_kernel<<<TB_/4, 256, 0, stream>>>(x, ln_g, ln_b, xnbf);
  lstm_scan<<<16, 512, 0, stream>>>(whhb, wihb, xnbf, x, first, h0, c0, bih, bhh,
                                    ymidb, HP, mode, hout, cout);
  for (int p = 0; p < 2; ++p) {
    const size_t ro = (size_t)p * 16384;
    gemm_bt<1,1><<<dim3(128, FF_/128), 256, 0, stream>>>(ymidb + ro * D_, m0bf, m0b,
                                                         nullptr, a1, 16384, FF_, D_);
    gemm_bt<0,0><<<dim3(128, D_/128), 256, 0, stream>>>(a1, m1bf, m1b,
                                                        out + ro * D_, nullptr, 16384, D_, FF_);
  }
  adapter_out_kernel<<<TB_/16, 256, 0, stream>>>(out, ymidb, awT0, awT1, ab0, ab1);
}

// Round 13
// 5113.395 us; speedup vs baseline: 3.2135x; 3.2135x over previous
//
#include <hip/hip_runtime.h>

#define T_ 1024
#define B_ 32
#define D_ 512
#define FF_ 2048
#define TB_ 32768   // T_*B_
#define TCH_ 512    // T half
#define RCH_ 16384  // TCH_*B_ rows per half

typedef short bf16x8 __attribute__((ext_vector_type(8)));
typedef float f32x4 __attribute__((ext_vector_type(4)));

static __device__ __forceinline__ unsigned int pack2bf(float a, float b){
  union { __bf16 h[2]; unsigned int u; } z;
  z.h[0] = (__bf16)a; z.h[1] = (__bf16)b; return z.u;
}
static __device__ __forceinline__ float bflo(unsigned int u){ return __uint_as_float(u<<16); }
static __device__ __forceinline__ float bfhi(unsigned int u){ return __uint_as_float(u & 0xffff0000u); }
static __device__ __forceinline__ float sigm(float x){ return 1.f/(1.f+__expf(-x)); }
static __device__ __forceinline__ float tanh_(float x){ return 1.f - 2.f/(1.f+__expf(2.f*x)); }

// first[] may be uint8 (numpy bool) or int32; detected at runtime.
static __device__ __forceinline__ bool firstval(const void* p, int mode, int idx){
  return mode ? (((const int*)p)[idx] != 0) : (((const unsigned char*)p)[idx] != 0);
}

// ---------------------------------------------------------------- detect bool dtype
__global__ void detect_first_kernel(const unsigned char* __restrict__ p, unsigned int* __restrict__ mode){
  __shared__ int found;
  if (threadIdx.x == 0) found = 0;
  __syncthreads();
  int f = 0;
  for (int i = threadIdx.x; i < TB_; i += 256) if ((i & 3) != 0 && p[i] != 0) f = 1;
  if (f) atomicAdd(&found, 1);
  __syncthreads();
  if (threadIdx.x == 0) *mode = (found == 0) ? 1u : 0u;   // 1 => int32, 0 => uint8
}

// ---------------------------------------------------------------- weight conversion
__global__ void convert_w_kernel(const float* __restrict__ Wih, const float* __restrict__ Whh,
                                 const float* __restrict__ m0w, const float* __restrict__ m1w,
                                 const float* __restrict__ aw0, const float* __restrict__ aw1,
                                 __bf16* __restrict__ Wihb, __bf16* __restrict__ Whhb,
                                 __bf16* __restrict__ m0b,  __bf16* __restrict__ m1b,
                                 __bf16* __restrict__ awT0, __bf16* __restrict__ awT1){
  int bid = blockIdx.x;
  if (bid < 4096) {
    int ai = bid >> 10;
    size_t off = (size_t)(bid & 1023) * 1024 + threadIdx.x * 4;
    const float* src = (ai==0)?Wih:(ai==1)?Whh:(ai==2)?m0w:m1w;
    __bf16* dst = (ai==0)?Wihb:(ai==1)?Whhb:(ai==2)?m0b:m1b;
    float4 v = *(const float4*)(src + off);
    union { __bf16 h[4]; uint2 u; } z;
    z.h[0]=(__bf16)v.x; z.h[1]=(__bf16)v.y; z.h[2]=(__bf16)v.z; z.h[3]=(__bf16)v.w;
    *(uint2*)(void*)(dst + off) = z.u;
  } else {
    int e = (bid - 4096) * 256 + threadIdx.x;      // 0..65535
    if (e < 32768) { int k = e >> 6, j = e & 63;  awT0[e] = (__bf16)aw0[j*512 + k]; }
    else { int e2 = e - 32768; int j = e2 >> 9, d = e2 & 511; awT1[e2] = (__bf16)aw1[d*64 + j]; }
  }
}

// ---------------------------------------------------------------- layernorm -> bf16 (half of rows)
__global__ __launch_bounds__(256) void ln_kernel(const float* __restrict__ x,
                                                 const float* __restrict__ g, const float* __restrict__ b,
                                                 __bf16* __restrict__ xn){
  const int w = threadIdx.x >> 6, l = threadIdx.x & 63;
  const int row = blockIdx.x * 4 + w;
  const float* xr = x + (size_t)row * D_;
  const int e0 = l * 4, e1 = 256 + l * 4;
  float4 v0 = *(const float4*)(xr + e0);
  float4 v1 = *(const float4*)(xr + e1);
  float s  = v0.x+v0.y+v0.z+v0.w + v1.x+v1.y+v1.z+v1.w;
  float s2 = v0.x*v0.x+v0.y*v0.y+v0.z*v0.z+v0.w*v0.w + v1.x*v1.x+v1.y*v1.y+v1.z*v1.z+v1.w*v1.w;
  #pragma unroll
  for (int off = 1; off < 64; off <<= 1) { s += __shfl_xor(s, off); s2 += __shfl_xor(s2, off); }
  float mu = s * (1.f/512.f);
  float var = s2 * (1.f/512.f) - mu*mu;
  float rstd = rsqrtf(var + 1e-5f);
  float4 g0 = *(const float4*)(g + e0), g1 = *(const float4*)(g + e1);
  float4 b0 = *(const float4*)(b + e0), b1 = *(const float4*)(b + e1);
  union { __bf16 h[4]; uint2 u; } o0, o1;
  o0.h[0]=(__bf16)((v0.x-mu)*rstd*g0.x+b0.x); o0.h[1]=(__bf16)((v0.y-mu)*rstd*g0.y+b0.y);
  o0.h[2]=(__bf16)((v0.z-mu)*rstd*g0.z+b0.z); o0.h[3]=(__bf16)((v0.w-mu)*rstd*g0.w+b0.w);
  o1.h[0]=(__bf16)((v1.x-mu)*rstd*g1.x+b1.x); o1.h[1]=(__bf16)((v1.y-mu)*rstd*g1.y+b1.y);
  o1.h[2]=(__bf16)((v1.z-mu)*rstd*g1.z+b1.z); o1.h[3]=(__bf16)((v1.w-mu)*rstd*g1.w+b1.w);
  *(uint2*)(void*)(xn + (size_t)row * D_ + e0) = o0.u;
  *(uint2*)(void*)(xn + (size_t)row * D_ + e1) = o1.u;
}

// ---------------------------------------------------------------- bf16 "BT" GEMM  C[M,N] = A[M,K] @ W[N,K]^T + bias (r6-proven)
template<int RELU, int BF16OUT, int TWOBIAS>
__global__ __launch_bounds__(256) void gemm_bt(const __bf16* __restrict__ A, const __bf16* __restrict__ W,
                                               const float* __restrict__ bias0, const float* __restrict__ bias1,
                                               float* __restrict__ Cf, __bf16* __restrict__ Cb,
                                               int M, int N, int K){
  __shared__ __bf16 As[128*64];
  __shared__ __bf16 Bs[128*64];
  const int tid = threadIdx.x, w = tid >> 6, l = tid & 63;
  const int bm = blockIdx.x, bn = blockIdx.y;
  const int wm = (w >> 1) * 64, wn = (w & 1) * 64;
  const int nk = K >> 6;

  uint4 ra[4], rb[4];
  #pragma unroll
  for (int i = 0; i < 4; ++i) {
    int s = tid + (i << 8); int row = s >> 3; int ks = s & 7;
    ra[i] = *(const uint4*)(void*)(A + (size_t)(bm*128 + row) * K + ks*8);
    rb[i] = *(const uint4*)(void*)(W + (size_t)(bn*128 + row) * K + ks*8);
  }
  f32x4 acc[4][4];
  #pragma unroll
  for (int mt = 0; mt < 4; ++mt)
    #pragma unroll
    for (int nt = 0; nt < 4; ++nt) acc[mt][nt] = (f32x4){0.f,0.f,0.f,0.f};

  for (int kt = 0; kt < nk; ++kt) {
    __syncthreads();
    #pragma unroll
    for (int i = 0; i < 4; ++i) {
      int s = tid + (i << 8); int row = s >> 3; int ks = s & 7;
      int wi = row * 64 + ((ks * 8) ^ ((row & 7) << 3));   // XOR swizzle (elements)
      *(uint4*)(void*)(As + wi) = ra[i];
      *(uint4*)(void*)(Bs + wi) = rb[i];
    }
    __syncthreads();
    if (kt + 1 < nk) {
      #pragma unroll
      for (int i = 0; i < 4; ++i) {
        int s = tid + (i << 8); int row = s >> 3; int ks = s & 7;
        ra[i] = *(const uint4*)(void*)(A + (size_t)(bm*128 + row) * K + (kt+1)*64 + ks*8);
        rb[i] = *(const uint4*)(void*)(W + (size_t)(bn*128 + row) * K + (kt+1)*64 + ks*8);
      }
    }
    #pragma unroll
    for (int kk = 0; kk < 2; ++kk) {
      bf16x8 af[4], bfv[4];
      const int ke = kk * 32 + ((l >> 4) << 3);
      #pragma unroll
      for (int mt = 0; mt < 4; ++mt) {
        int row = wm + mt*16 + (l & 15);
        af[mt] = *(const bf16x8*)(void*)(As + row*64 + (ke ^ ((row & 7) << 3)));
      }
      #pragma unroll
      for (int nt = 0; nt < 4; ++nt) {
        int row = wn + nt*16 + (l & 15);
        bfv[nt] = *(const bf16x8*)(void*)(Bs + row*64 + (ke ^ ((row & 7) << 3)));
      }
      #pragma unroll
      for (int mt = 0; mt < 4; ++mt)
        #pragma unroll
        for (int nt = 0; nt < 4; ++nt)
          acc[mt][nt] = __builtin_amdgcn_mfma_f32_16x16x32_bf16(af[mt], bfv[nt], acc[mt][nt], 0, 0, 0);
    }
  }
  // epilogue: D row = (l>>4)*4+j, col = l&15 (m89-verified layout)
  #pragma unroll
  for (int nt = 0; nt < 4; ++nt) {
    int c = bn*128 + wn + nt*16 + (l & 15);
    float bv = bias0[c];
    if (TWOBIAS) bv += bias1[c];
    #pragma unroll
    for (int mt = 0; mt < 4; ++mt) {
      #pragma unroll
      for (int j = 0; j < 4; ++j) {
        int r = bm*128 + wm + mt*16 + ((l >> 4) << 2) + j;
        float v = acc[mt][nt][j] + bv;
        if (RELU) v = fmaxf(v, 0.f);
        if (BF16OUT) Cb[(size_t)r * N + c] = (__bf16)v;
        else         Cf[(size_t)r * N + c] = v;
      }
    }
  }
}

// ---------------------------------------------------------------- LSTM scan half (r6-proven packet protocol, TCH_=512)
__global__ __launch_bounds__(512) void lstm_scan(
    const __bf16* __restrict__ Whh,      // [2048][512] bf16
    const __bf16* __restrict__ preC,     // [RCH_][2048] bf16 (half-local rows)
    const float*  __restrict__ x,        // residual (global rows)
    const void*   __restrict__ firstp,
    const float*  __restrict__ h0,
    const float*  __restrict__ c0,
    float*        __restrict__ cstate,   // [B_*D_] f32 (pre-multiplied by keep)
    __bf16*       __restrict__ ymidbC,   // [RCH_][512] bf16 (half-local rows)
    unsigned long long* __restrict__ HP, // [2][8192] packets
    const unsigned int* __restrict__ modep,
    float* __restrict__ hout, float* __restrict__ cout,
    int tBase){
  const int s = blockIdx.x, tid = threadIdx.x, w = tid >> 6, l = tid & 63;
  const int d0 = s * 32;
  __shared__ __bf16 Hl[32 * 512];      // staged H, stride 512 + XOR swizzle (2-way max)
  __shared__ float  gl[32 * 132];      // gate exchange, stride 132 (2-way max)
  const int mode = (int)*modep;

  // Whh B-fragments resident in VGPRs: wave w owns gate rows rl = w*16 + (l&15)
  bf16x8 wf[16];
  {
    int rl = w*16 + (l & 15);
    int gr = (rl >> 5) * 512 + d0 + (rl & 31);     // PyTorch gate order i,f,g,o
    const __bf16* base = Whh + (size_t)gr * 512 + ((l >> 4) << 3);
    #pragma unroll
    for (int kt = 0; kt < 16; ++kt) wf[kt] = *(const bf16x8*)(void*)(base + kt*32);
  }
  const int b = tid >> 4, dl2 = (tid & 15) * 2;    // producer role: (batch, dim pair)
  const int dg = d0 + dl2;
  const int opid = b * 256 + s * 16 + (tid & 15);  // own packet id

  float cr[2];
  if (tBase == 0) {
    float k0 = firstval(firstp, mode, b) ? 0.f : 1.f;
    float2 c2 = *(const float2*)(c0 + (size_t)b*512 + dg);
    cr[0] = c2.x * k0; cr[1] = c2.y * k0;
    float2 h = *(const float2*)(h0 + (size_t)b*512 + dg);
    unsigned long long pkt = (1ULL << 32) | (unsigned long long)pack2bf(h.x*k0, h.y*k0);
    __hip_atomic_store(HP + opid, pkt, __ATOMIC_RELAXED, __HIP_MEMORY_SCOPE_AGENT);
  } else {
    float2 c2 = *(const float2*)(cstate + (size_t)b*512 + dg);
    cr[0] = c2.x; cr[1] = c2.y;
  }

  for (int tl = 0; tl < TCH_; ++tl) {
    const int t = tBase + tl;
    const int rowg = t * 32 + b, rowl = tl * 32 + b;
    // prefetch (overlaps the poll below)
    unsigned int pg[4];
    #pragma unroll
    for (int gi = 0; gi < 4; ++gi)
      pg[gi] = *(const unsigned int*)(void*)(preC + (size_t)rowl * 2048 + gi*512 + dg);
    float2 xv = *(const float2*)(x + (size_t)rowg * 512 + dg);
    const bool f_t1 = (t < T_-1) ? firstval(firstp, mode, rowg + 32) : false;

    // ---- poll: coalesced packet loads (thread tid owns pids {tid + j*512})
    const unsigned want = (unsigned)(t + 1);
    const unsigned long long* Pb = HP + ((size_t)(t & 1) << 13);
    unsigned long long pk[16];
    #pragma unroll
    for (int j = 0; j < 16; ++j)
      pk[j] = __hip_atomic_load(Pb + tid + (j << 9), __ATOMIC_RELAXED, __HIP_MEMORY_SCOPE_AGENT);
    while (true) {
      unsigned stale = 0;
      #pragma unroll
      for (int j = 0; j < 16; ++j)
        if ((unsigned)(pk[j] >> 32) != want) stale |= (1u << j);
      if (!stale) break;
      __builtin_amdgcn_s_sleep(1);
      #pragma unroll
      for (int j = 0; j < 16; ++j)
        if (stale & (1u << j))
          pk[j] = __hip_atomic_load(Pb + tid + (j << 9), __ATOMIC_RELAXED, __HIP_MEMORY_SCOPE_AGENT);
    }
    // payloads -> LDS: pid = pb*256 + ps*16 + pi -> row pb, elems ps*32 + pi*2 (swizzled)
    #pragma unroll
    for (int j = 0; j < 16; ++j) {
      int pid = tid + (j << 9);
      int pb = pid >> 8, ps = (pid >> 4) & 15, pi = pid & 15;
      int q = ps*32 + pi*2;
      *(unsigned int*)(void*)(Hl + pb*512 + (q ^ ((pb & 7) << 3))) = (unsigned)pk[j];
    }
    __syncthreads();

    // ---- gates[b, rl] = H @ Whh_slice^T  (2 interleaved chains per acc, 8-deep)
    f32x4 a0a = (f32x4){0.f,0.f,0.f,0.f}, a0b = (f32x4){0.f,0.f,0.f,0.f};
    f32x4 a1a = (f32x4){0.f,0.f,0.f,0.f}, a1b = (f32x4){0.f,0.f,0.f,0.f};
    #pragma unroll
    for (int kt = 0; kt < 16; kt += 2) {
      int ke0 = kt*32 + ((l >> 4) << 3), ke1 = (kt+1)*32 + ((l >> 4) << 3);
      int r0 = (l & 15), r1 = 16 + (l & 15);
      bf16x8 h00 = *(const bf16x8*)(void*)(Hl + r0*512 + (ke0 ^ ((r0 & 7) << 3)));
      bf16x8 h01 = *(const bf16x8*)(void*)(Hl + r0*512 + (ke1 ^ ((r0 & 7) << 3)));
      bf16x8 h10 = *(const bf16x8*)(void*)(Hl + r1*512 + (ke0 ^ ((r1 & 7) << 3)));
      bf16x8 h11 = *(const bf16x8*)(void*)(Hl + r1*512 + (ke1 ^ ((r1 & 7) << 3)));
      a0a = __builtin_amdgcn_mfma_f32_16x16x32_bf16(h00, wf[kt],   a0a, 0, 0, 0);
      a0b = __builtin_amdgcn_mfma_f32_16x16x32_bf16(h01, wf[kt+1], a0b, 0, 0, 0);
      a1a = __builtin_amdgcn_mfma_f32_16x16x32_bf16(h10, wf[kt],   a1a, 0, 0, 0);
      a1b = __builtin_amdgcn_mfma_f32_16x16x32_bf16(h11, wf[kt+1], a1b, 0, 0, 0);
    }
    f32x4 acc0 = a0a + a0b, acc1 = a1a + a1b;
    // ---- gate exchange through LDS (stride 132: 2-way max both sides)
    {
      int col = w*16 + (l & 15);
      #pragma unroll
      for (int j = 0; j < 4; ++j) {
        gl[(((l >> 4) << 2) + j) * 132 + col]        = acc0[j];
        gl[((16 + ((l >> 4) << 2) + j)) * 132 + col] = acc1[j];
      }
    }
    __syncthreads();

    // ---- cell update for (b, dg), (b, dg+1); cr pre-multiplied by keep(first[t])
    float2 gv[4];
    #pragma unroll
    for (int gi = 0; gi < 4; ++gi) gv[gi] = *(const float2*)(gl + b*132 + gi*32 + dl2);
    const float keep1 = f_t1 ? 0.f : 1.f;
    float hh[2], cc[2];
    #pragma unroll
    for (int p = 0; p < 2; ++p) {
      float gi_ = (p ? gv[0].y : gv[0].x) + (p ? bfhi(pg[0]) : bflo(pg[0]));
      float gf_ = (p ? gv[1].y : gv[1].x) + (p ? bfhi(pg[1]) : bflo(pg[1]));
      float gg_ = (p ? gv[2].y : gv[2].x) + (p ? bfhi(pg[2]) : bflo(pg[2]));
      float go_ = (p ? gv[3].y : gv[3].x) + (p ? bfhi(pg[3]) : bflo(pg[3]));
      float cn = sigm(gf_) * cr[p] + sigm(gi_) * tanh_(gg_);
      float h  = sigm(go_) * tanh_(cn);
      cc[p] = cn; hh[p] = h;
    }
    cr[0] = cc[0] * keep1; cr[1] = cc[1] * keep1;
    float2 yv = { hh[0] + xv.x, hh[1] + xv.y };
    if (t < T_-1) {
      // publish own packet (tag t+2) -- payload rides with the tag (release)
      unsigned long long pkt = (((unsigned long long)(unsigned)(t + 2)) << 32)
                             | (unsigned long long)pack2bf(hh[0]*keep1, hh[1]*keep1);
      __hip_atomic_store(HP + (((size_t)((t+1) & 1)) << 13) + opid, pkt,
                         __ATOMIC_RELAXED, __HIP_MEMORY_SCOPE_AGENT);
      if (tl == TCH_-1) *(float2*)(cstate + (size_t)b*512 + dg) = make_float2(cr[0], cr[1]);
    } else {
      *(float2*)(hout + (size_t)b*512 + dg) = make_float2(hh[0], hh[1]);
      *(float2*)(cout + (size_t)b*512 + dg) = make_float2(cc[0], cc[1]);
    }
    // no end-of-iter barrier: next iteration's post-stage __syncthreads orders LDS reuse.
    *(unsigned int*)(void*)(ymidbC + (size_t)rowl * 512 + dg) = pack2bf(yv.x, yv.y);
  }
}

// ---------------------------------------------------------------- fused adapter + final residual (in-place on y2)
__global__ __launch_bounds__(256) void adapter_out_kernel(
    float* __restrict__ y2,              // [RCH_][512] in/out (lives in d_out)
    const __bf16* __restrict__ ymidb,    // [RCH_][512]
    const __bf16* __restrict__ awT0,     // [512][64] = aw0^T
    const __bf16* __restrict__ awT1,     // [64][512] = aw1^T
    const float* __restrict__ ab0, const float* __restrict__ ab1){
  __shared__ float zl[16 * 64];
  const int w = threadIdx.x >> 6, l = threadIdx.x & 63;
  const int r0 = blockIdx.x * 16;
  const float bz = ab0[l];
  #pragma unroll
  for (int rr = 0; rr < 4; ++rr) {
    int rowl = w*4 + rr;
    const float* yr = y2 + (size_t)(r0 + rowl) * 512;
    float acc = bz;
    #pragma unroll 4
    for (int k = 0; k < 512; ++k) acc += yr[k] * (float)awT0[k*64 + l];
    zl[rowl*64 + l] = fmaxf(acc, 0.f);
  }
  __syncthreads();
  #pragma unroll
  for (int rr = 0; rr < 4; ++rr) {
    int rowl = w*4 + rr; int row = r0 + rowl;
    const float* yr = y2  + (size_t)row * 512;
    const __bf16* mr = ymidb + (size_t)row * 512;
    #pragma unroll
    for (int dd = 0; dd < 8; ++dd) {
      int d = dd*64 + l;
      float acc = ab1[d] + yr[d] + (float)mr[d];
      #pragma unroll 4
      for (int j = 0; j < 64; ++j) acc += zl[rowl*64 + j] * (float)awT1[j*512 + d];
      y2[(size_t)row * 512 + d] = acc;
    }
  }
}

// ---------------------------------------------------------------- launch
extern "C" void kernel_launch(void* const* d_in, const int* in_sizes, int n_in,
                              void* d_out, int out_size, void* d_ws, size_t ws_size,
                              hipStream_t stream){
  (void)in_sizes; (void)n_in; (void)out_size; (void)ws_size;
  const float* x    = (const float*)d_in[0];
  const void*  first=               d_in[1];
  const float* h0   = (const float*)d_in[2];
  const float* c0   = (const float*)d_in[3];
  const float* ln_g = (const float*)d_in[4];
  const float* ln_b = (const float*)d_in[5];
  const float* Wih  = (const float*)d_in[6];
  const float* Whh  = (const float*)d_in[7];
  const float* bih  = (const float*)d_in[8];
  const float* bhh  = (const float*)d_in[9];
  const float* m0w  = (const float*)d_in[10];
  const float* m0b  = (const float*)d_in[11];
  const float* m1w  = (const float*)d_in[12];
  const float* m1b  = (const float*)d_in[13];
  const float* aw0  = (const float*)d_in[14];
  const float* ab0  = (const float*)d_in[15];
  const float* aw1  = (const float*)d_in[16];
  const float* ab1  = (const float*)d_in[17];

  // workspace layout — ~109.4 MB (< 126 MB proven available in r10/r11 Plan-A runs)
  char* ws = (char*)d_ws;
  __bf16* buf0  = (__bf16*)(ws + 0LL);             // 64 MB: preH, later a1 (disjoint lifetimes per half)
  __bf16* xnbfH = (__bf16*)(ws + 67108864LL);      // 16 MB
  __bf16* ymidbH= (__bf16*)(ws + 83886080LL);      // 16 MB
  __bf16* wihb  = (__bf16*)(ws + 100663296LL);     // 2 MB
  __bf16* whhb  = (__bf16*)(ws + 102760448LL);     // 2 MB
  __bf16* m0bf  = (__bf16*)(ws + 104857600LL);     // 2 MB
  __bf16* m1bf  = (__bf16*)(ws + 106954752LL);     // 2 MB
  __bf16* awT0  = (__bf16*)(ws + 109051904LL);     // 64 KB
  __bf16* awT1  = (__bf16*)(ws + 109117440LL);     // 64 KB
  unsigned long long* HP = (unsigned long long*)(ws + 109182976LL);  // 128 KB
  float*  cstate= (float*) (ws + 109314048LL);     // 64 KB
  unsigned int* mode = (unsigned int*)(ws + 109379584LL);
  __bf16* preH = buf0;
  __bf16* a1   = buf0;                             // alias (disjoint lifetime)

  float* out  = (float*)d_out;
  float* hout = out + (size_t)TB_ * D_;
  float* cout = hout + B_ * D_;

  hipMemsetAsync(HP, 0, 131072, stream);           // kill cross-replay stale tags
  detect_first_kernel<<<1, 256, 0, stream>>>((const unsigned char*)first, mode);
  convert_w_kernel<<<4352, 256, 0, stream>>>(Wih, Whh, m0w, m1w, aw0, aw1,
                                             wihb, whhb, m0bf, m1bf, awT0, awT1);
  for (int h = 0; h < 2; ++h) {
    const size_t ro = (size_t)h * RCH_;
    ln_kernel<<<RCH_/4, 256, 0, stream>>>(x + ro * D_, ln_g, ln_b, xnbfH);
    gemm_bt<0,1,1><<<dim3(RCH_/128, FF_/128), 256, 0, stream>>>(xnbfH, wihb, bih, bhh,
                                                                nullptr, preH, RCH_, 2048, 512);
    lstm_scan<<<16, 512, 0, stream>>>(whhb, preH, x, first, h0, c0, cstate, ymidbH,
                                      HP, mode, hout, cout, h * TCH_);
    gemm_bt<1,1,0><<<dim3(RCH_/128, FF_/128), 256, 0, stream>>>(ymidbH, m0bf, m0b, nullptr,
                                                                nullptr, a1, RCH_, FF_, 512);
    gemm_bt<0,0,0><<<dim3(RCH_/128, D_/128), 256, 0, stream>>>(a1, m1bf, m1b, nullptr,
                                                               out + ro * D_, nullptr, RCH_, D_, FF_);
    adapter_out_kernel<<<RCH_/16, 256, 0, stream>>>(out + ro * D_, ymidbH, awT0, awT1, ab0, ab1);
  }
}

// Round 14
// 4377.324 us; speedup vs baseline: 3.7538x; 1.1682x over previous
//
#include <hip/hip_runtime.h>

#define T_ 1024
#define B_ 32
#define D_ 512
#define FF_ 2048
#define TB_ 32768   // T_*B_
#define TCH_ 512    // T half
#define RCH_ 16384  // TCH_*B_ rows per half

typedef short bf16x8 __attribute__((ext_vector_type(8)));
typedef float f32x4 __attribute__((ext_vector_type(4)));

static __device__ __forceinline__ unsigned int pack2bf(float a, float b){
  union { __bf16 h[2]; unsigned int u; } z;
  z.h[0] = (__bf16)a; z.h[1] = (__bf16)b; return z.u;
}
static __device__ __forceinline__ float bflo(unsigned int u){ return __uint_as_float(u<<16); }
static __device__ __forceinline__ float bfhi(unsigned int u){ return __uint_as_float(u & 0xffff0000u); }
static __device__ __forceinline__ float sigm(float x){ return 1.f/(1.f+__expf(-x)); }
static __device__ __forceinline__ float tanh_(float x){ return 1.f - 2.f/(1.f+__expf(2.f*x)); }

// async global->LDS, 16B per lane; LDS dest is wave-uniform base + lane*16
static __device__ __forceinline__ void gload16(const __bf16* g, __bf16* l){
  __builtin_amdgcn_global_load_lds(
      (__attribute__((address_space(1))) const void*)g,
      (__attribute__((address_space(3))) void*)l, 16, 0, 0);
}

// first[] may be uint8 (numpy bool) or int32; detected at runtime.
static __device__ __forceinline__ bool firstval(const void* p, int mode, int idx){
  return mode ? (((const int*)p)[idx] != 0) : (((const unsigned char*)p)[idx] != 0);
}

// ---------------------------------------------------------------- detect bool dtype
__global__ void detect_first_kernel(const unsigned char* __restrict__ p, unsigned int* __restrict__ mode){
  __shared__ int found;
  if (threadIdx.x == 0) found = 0;
  __syncthreads();
  int f = 0;
  for (int i = threadIdx.x; i < TB_; i += 256) if ((i & 3) != 0 && p[i] != 0) f = 1;
  if (f) atomicAdd(&found, 1);
  __syncthreads();
  if (threadIdx.x == 0) *mode = (found == 0) ? 1u : 0u;   // 1 => int32, 0 => uint8
}

// ---------------------------------------------------------------- weight conversion
__global__ void convert_w_kernel(const float* __restrict__ Wih, const float* __restrict__ Whh,
                                 const float* __restrict__ m0w, const float* __restrict__ m1w,
                                 const float* __restrict__ aw0, const float* __restrict__ aw1,
                                 __bf16* __restrict__ Wihb, __bf16* __restrict__ Whhb,
                                 __bf16* __restrict__ m0b,  __bf16* __restrict__ m1b,
                                 float* __restrict__ awT0f, float* __restrict__ awT1f){
  int bid = blockIdx.x;
  if (bid < 4096) {
    int ai = bid >> 10;
    size_t off = (size_t)(bid & 1023) * 1024 + threadIdx.x * 4;
    const float* src = (ai==0)?Wih:(ai==1)?Whh:(ai==2)?m0w:m1w;
    __bf16* dst = (ai==0)?Wihb:(ai==1)?Whhb:(ai==2)?m0b:m1b;
    float4 v = *(const float4*)(src + off);
    union { __bf16 h[4]; uint2 u; } z;
    z.h[0]=(__bf16)v.x; z.h[1]=(__bf16)v.y; z.h[2]=(__bf16)v.z; z.h[3]=(__bf16)v.w;
    *(uint2*)(void*)(dst + off) = z.u;
  } else {
    int e = (bid - 4096) * 256 + threadIdx.x;      // 0..65535
    if (e < 32768) { int k = e >> 6, j = e & 63;  awT0f[e] = aw0[j*512 + k]; }
    else { int e2 = e - 32768; int j = e2 >> 9, d = e2 & 511; awT1f[e2] = aw1[d*64 + j]; }
  }
}

// ---------------------------------------------------------------- layernorm -> bf16 (half of rows)
__global__ __launch_bounds__(256) void ln_kernel(const float* __restrict__ x,
                                                 const float* __restrict__ g, const float* __restrict__ b,
                                                 __bf16* __restrict__ xn){
  const int w = threadIdx.x >> 6, l = threadIdx.x & 63;
  const int row = blockIdx.x * 4 + w;
  const float* xr = x + (size_t)row * D_;
  const int e0 = l * 4, e1 = 256 + l * 4;
  float4 v0 = *(const float4*)(xr + e0);
  float4 v1 = *(const float4*)(xr + e1);
  float s  = v0.x+v0.y+v0.z+v0.w + v1.x+v1.y+v1.z+v1.w;
  float s2 = v0.x*v0.x+v0.y*v0.y+v0.z*v0.z+v0.w*v0.w + v1.x*v1.x+v1.y*v1.y+v1.z*v1.z+v1.w*v1.w;
  #pragma unroll
  for (int off = 1; off < 64; off <<= 1) { s += __shfl_xor(s, off); s2 += __shfl_xor(s2, off); }
  float mu = s * (1.f/512.f);
  float var = s2 * (1.f/512.f) - mu*mu;
  float rstd = rsqrtf(var + 1e-5f);
  float4 g0 = *(const float4*)(g + e0), g1 = *(const float4*)(g + e1);
  float4 b0 = *(const float4*)(b + e0), b1 = *(const float4*)(b + e1);
  union { __bf16 h[4]; uint2 u; } o0, o1;
  o0.h[0]=(__bf16)((v0.x-mu)*rstd*g0.x+b0.x); o0.h[1]=(__bf16)((v0.y-mu)*rstd*g0.y+b0.y);
  o0.h[2]=(__bf16)((v0.z-mu)*rstd*g0.z+b0.z); o0.h[3]=(__bf16)((v0.w-mu)*rstd*g0.w+b0.w);
  o1.h[0]=(__bf16)((v1.x-mu)*rstd*g1.x+b1.x); o1.h[1]=(__bf16)((v1.y-mu)*rstd*g1.y+b1.y);
  o1.h[2]=(__bf16)((v1.z-mu)*rstd*g1.z+b1.z); o1.h[3]=(__bf16)((v1.w-mu)*rstd*g1.w+b1.w);
  *(uint2*)(void*)(xn + (size_t)row * D_ + e0) = o0.u;
  *(uint2*)(void*)(xn + (size_t)row * D_ + e1) = o1.u;
}

// ---------------------------------------------------------------- bf16 "BT" GEMM via global_load_lds (m97 structure)
// LDS tile stored with the XOR swizzle applied to the GLOBAL SOURCE address
// (LDS write is linear per HW requirement); reads keep the swizzled addressing.
template<int RELU, int BF16OUT, int TWOBIAS>
__global__ __launch_bounds__(256) void gemm_bt(const __bf16* __restrict__ A, const __bf16* __restrict__ W,
                                               const float* __restrict__ bias0, const float* __restrict__ bias1,
                                               float* __restrict__ Cf, __bf16* __restrict__ Cb,
                                               int M, int N, int K){
  __shared__ __bf16 As[128*64];
  __shared__ __bf16 Bs[128*64];
  const int tid = threadIdx.x, w = tid >> 6, l = tid & 63;
  const int bm = blockIdx.x, bn = blockIdx.y;
  const int wm = (w >> 1) * 64, wn = (w & 1) * 64;
  const int nk = K >> 6;

  // chunk c = i*256 + w*64 + l : row = c>>3, source elem = (c&7)*8 ^ ((row&7)<<3)
  int crow[4], ksrc[4];
  #pragma unroll
  for (int i = 0; i < 4; ++i) {
    int c = i*256 + w*64 + l;
    crow[i] = c >> 3;
    ksrc[i] = ((c & 7) * 8) ^ ((crow[i] & 7) << 3);
  }

  f32x4 acc[4][4];
  #pragma unroll
  for (int mt = 0; mt < 4; ++mt)
    #pragma unroll
    for (int nt = 0; nt < 4; ++nt) acc[mt][nt] = (f32x4){0.f,0.f,0.f,0.f};

  for (int kt = 0; kt < nk; ++kt) {
    if (kt) __syncthreads();             // readers of previous tile done
    #pragma unroll
    for (int i = 0; i < 4; ++i) {
      const __bf16* ga = A + (size_t)(bm*128 + crow[i]) * K + kt*64 + ksrc[i];
      const __bf16* gb = W + (size_t)(bn*128 + crow[i]) * K + kt*64 + ksrc[i];
      gload16(ga, As + (size_t)(i*256 + w*64) * 8);
      gload16(gb, Bs + (size_t)(i*256 + w*64) * 8);
    }
    __syncthreads();                     // barrier drains vmcnt -> LDS tile ready
    #pragma unroll
    for (int kk = 0; kk < 2; ++kk) {
      bf16x8 af[4], bfv[4];
      const int ke = kk * 32 + ((l >> 4) << 3);
      #pragma unroll
      for (int mt = 0; mt < 4; ++mt) {
        int row = wm + mt*16 + (l & 15);
        af[mt] = *(const bf16x8*)(void*)(As + row*64 + (ke ^ ((row & 7) << 3)));
      }
      #pragma unroll
      for (int nt = 0; nt < 4; ++nt) {
        int row = wn + nt*16 + (l & 15);
        bfv[nt] = *(const bf16x8*)(void*)(Bs + row*64 + (ke ^ ((row & 7) << 3)));
      }
      #pragma unroll
      for (int mt = 0; mt < 4; ++mt)
        #pragma unroll
        for (int nt = 0; nt < 4; ++nt)
          acc[mt][nt] = __builtin_amdgcn_mfma_f32_16x16x32_bf16(af[mt], bfv[nt], acc[mt][nt], 0, 0, 0);
    }
  }
  // epilogue: D row = (l>>4)*4+j, col = l&15 (m89-verified layout)
  #pragma unroll
  for (int nt = 0; nt < 4; ++nt) {
    int c = bn*128 + wn + nt*16 + (l & 15);
    float bv = bias0[c];
    if (TWOBIAS) bv += bias1[c];
    #pragma unroll
    for (int mt = 0; mt < 4; ++mt) {
      #pragma unroll
      for (int j = 0; j < 4; ++j) {
        int r = bm*128 + wm + mt*16 + ((l >> 4) << 2) + j;
        float v = acc[mt][nt][j] + bv;
        if (RELU) v = fmaxf(v, 0.f);
        if (BF16OUT) Cb[(size_t)r * N + c] = (__bf16)v;
        else         Cf[(size_t)r * N + c] = v;
      }
    }
  }
}

// ---------------------------------------------------------------- LSTM scan half (r6-proven packet protocol, TCH_=512)
__global__ __launch_bounds__(512) void lstm_scan(
    const __bf16* __restrict__ Whh,      // [2048][512] bf16
    const __bf16* __restrict__ preC,     // [RCH_][2048] bf16 (half-local rows)
    const float*  __restrict__ x,        // residual (global rows)
    const void*   __restrict__ firstp,
    const float*  __restrict__ h0,
    const float*  __restrict__ c0,
    float*        __restrict__ cstate,   // [B_*D_] f32 (pre-multiplied by keep)
    __bf16*       __restrict__ ymidbC,   // [RCH_][512] bf16 (half-local rows)
    unsigned long long* __restrict__ HP, // [2][8192] packets
    const unsigned int* __restrict__ modep,
    float* __restrict__ hout, float* __restrict__ cout,
    int tBase){
  const int s = blockIdx.x, tid = threadIdx.x, w = tid >> 6, l = tid & 63;
  const int d0 = s * 32;
  __shared__ __bf16 Hl[32 * 512];      // staged H, stride 512 + XOR swizzle (2-way max)
  __shared__ float  gl[32 * 132];      // gate exchange, stride 132 (2-way max)
  const int mode = (int)*modep;

  // Whh B-fragments resident in VGPRs: wave w owns gate rows rl = w*16 + (l&15)
  bf16x8 wf[16];
  {
    int rl = w*16 + (l & 15);
    int gr = (rl >> 5) * 512 + d0 + (rl & 31);     // PyTorch gate order i,f,g,o
    const __bf16* base = Whh + (size_t)gr * 512 + ((l >> 4) << 3);
    #pragma unroll
    for (int kt = 0; kt < 16; ++kt) wf[kt] = *(const bf16x8*)(void*)(base + kt*32);
  }
  const int b = tid >> 4, dl2 = (tid & 15) * 2;    // producer role: (batch, dim pair)
  const int dg = d0 + dl2;
  const int opid = b * 256 + s * 16 + (tid & 15);  // own packet id

  float cr[2];
  if (tBase == 0) {
    float k0 = firstval(firstp, mode, b) ? 0.f : 1.f;
    float2 c2 = *(const float2*)(c0 + (size_t)b*512 + dg);
    cr[0] = c2.x * k0; cr[1] = c2.y * k0;
    float2 h = *(const float2*)(h0 + (size_t)b*512 + dg);
    unsigned long long pkt = (1ULL << 32) | (unsigned long long)pack2bf(h.x*k0, h.y*k0);
    __hip_atomic_store(HP + opid, pkt, __ATOMIC_RELAXED, __HIP_MEMORY_SCOPE_AGENT);
  } else {
    float2 c2 = *(const float2*)(cstate + (size_t)b*512 + dg);
    cr[0] = c2.x; cr[1] = c2.y;
  }

  for (int tl = 0; tl < TCH_; ++tl) {
    const int t = tBase + tl;
    const int rowg = t * 32 + b, rowl = tl * 32 + b;
    // prefetch (overlaps the poll below)
    unsigned int pg[4];
    #pragma unroll
    for (int gi = 0; gi < 4; ++gi)
      pg[gi] = *(const unsigned int*)(void*)(preC + (size_t)rowl * 2048 + gi*512 + dg);
    float2 xv = *(const float2*)(x + (size_t)rowg * 512 + dg);
    const bool f_t1 = (t < T_-1) ? firstval(firstp, mode, rowg + 32) : false;

    // ---- poll: coalesced packet loads (thread tid owns pids {tid + j*512})
    const unsigned want = (unsigned)(t + 1);
    const unsigned long long* Pb = HP + ((size_t)(t & 1) << 13);
    unsigned long long pk[16];
    #pragma unroll
    for (int j = 0; j < 16; ++j)
      pk[j] = __hip_atomic_load(Pb + tid + (j << 9), __ATOMIC_RELAXED, __HIP_MEMORY_SCOPE_AGENT);
    while (true) {
      unsigned stale = 0;
      #pragma unroll
      for (int j = 0; j < 16; ++j)
        if ((unsigned)(pk[j] >> 32) != want) stale |= (1u << j);
      if (!stale) break;
      __builtin_amdgcn_s_sleep(1);
      #pragma unroll
      for (int j = 0; j < 16; ++j)
        if (stale & (1u << j))
          pk[j] = __hip_atomic_load(Pb + tid + (j << 9), __ATOMIC_RELAXED, __HIP_MEMORY_SCOPE_AGENT);
    }
    // payloads -> LDS: pid = pb*256 + ps*16 + pi -> row pb, elems ps*32 + pi*2 (swizzled)
    #pragma unroll
    for (int j = 0; j < 16; ++j) {
      int pid = tid + (j << 9);
      int pb = pid >> 8, ps = (pid >> 4) & 15, pi = pid & 15;
      int q = ps*32 + pi*2;
      *(unsigned int*)(void*)(Hl + pb*512 + (q ^ ((pb & 7) << 3))) = (unsigned)pk[j];
    }
    __syncthreads();

    // ---- gates[b, rl] = H @ Whh_slice^T  (2 interleaved chains per acc, 8-deep)
    f32x4 a0a = (f32x4){0.f,0.f,0.f,0.f}, a0b = (f32x4){0.f,0.f,0.f,0.f};
    f32x4 a1a = (f32x4){0.f,0.f,0.f,0.f}, a1b = (f32x4){0.f,0.f,0.f,0.f};
    #pragma unroll
    for (int kt = 0; kt < 16; kt += 2) {
      int ke0 = kt*32 + ((l >> 4) << 3), ke1 = (kt+1)*32 + ((l >> 4) << 3);
      int r0 = (l & 15), r1 = 16 + (l & 15);
      bf16x8 h00 = *(const bf16x8*)(void*)(Hl + r0*512 + (ke0 ^ ((r0 & 7) << 3)));
      bf16x8 h01 = *(const bf16x8*)(void*)(Hl + r0*512 + (ke1 ^ ((r0 & 7) << 3)));
      bf16x8 h10 = *(const bf16x8*)(void*)(Hl + r1*512 + (ke0 ^ ((r1 & 7) << 3)));
      bf16x8 h11 = *(const bf16x8*)(void*)(Hl + r1*512 + (ke1 ^ ((r1 & 7) << 3)));
      a0a = __builtin_amdgcn_mfma_f32_16x16x32_bf16(h00, wf[kt],   a0a, 0, 0, 0);
      a0b = __builtin_amdgcn_mfma_f32_16x16x32_bf16(h01, wf[kt+1], a0b, 0, 0, 0);
      a1a = __builtin_amdgcn_mfma_f32_16x16x32_bf16(h10, wf[kt],   a1a, 0, 0, 0);
      a1b = __builtin_amdgcn_mfma_f32_16x16x32_bf16(h11, wf[kt+1], a1b, 0, 0, 0);
    }
    f32x4 acc0 = a0a + a0b, acc1 = a1a + a1b;
    // ---- gate exchange through LDS (stride 132: 2-way max both sides)
    {
      int col = w*16 + (l & 15);
      #pragma unroll
      for (int j = 0; j < 4; ++j) {
        gl[(((l >> 4) << 2) + j) * 132 + col]        = acc0[j];
        gl[((16 + ((l >> 4) << 2) + j)) * 132 + col] = acc1[j];
      }
    }
    __syncthreads();

    // ---- cell update for (b, dg), (b, dg+1); cr pre-multiplied by keep(first[t])
    float2 gv[4];
    #pragma unroll
    for (int gi = 0; gi < 4; ++gi) gv[gi] = *(const float2*)(gl + b*132 + gi*32 + dl2);
    const float keep1 = f_t1 ? 0.f : 1.f;
    float hh[2], cc[2];
    #pragma unroll
    for (int p = 0; p < 2; ++p) {
      float gi_ = (p ? gv[0].y : gv[0].x) + (p ? bfhi(pg[0]) : bflo(pg[0]));
      float gf_ = (p ? gv[1].y : gv[1].x) + (p ? bfhi(pg[1]) : bflo(pg[1]));
      float gg_ = (p ? gv[2].y : gv[2].x) + (p ? bfhi(pg[2]) : bflo(pg[2]));
      float go_ = (p ? gv[3].y : gv[3].x) + (p ? bfhi(pg[3]) : bflo(pg[3]));
      float cn = sigm(gf_) * cr[p] + sigm(gi_) * tanh_(gg_);
      float h  = sigm(go_) * tanh_(cn);
      cc[p] = cn; hh[p] = h;
    }
    cr[0] = cc[0] * keep1; cr[1] = cc[1] * keep1;
    float2 yv = { hh[0] + xv.x, hh[1] + xv.y };
    if (t < T_-1) {
      // publish own packet (tag t+2) -- payload rides with the tag (release)
      unsigned long long pkt = (((unsigned long long)(unsigned)(t + 2)) << 32)
                             | (unsigned long long)pack2bf(hh[0]*keep1, hh[1]*keep1);
      __hip_atomic_store(HP + (((size_t)((t+1) & 1)) << 13) + opid, pkt,
                         __ATOMIC_RELAXED, __HIP_MEMORY_SCOPE_AGENT);
      if (tl == TCH_-1) *(float2*)(cstate + (size_t)b*512 + dg) = make_float2(cr[0], cr[1]);
    } else {
      *(float2*)(hout + (size_t)b*512 + dg) = make_float2(hh[0], hh[1]);
      *(float2*)(cout + (size_t)b*512 + dg) = make_float2(cc[0], cc[1]);
    }
    // no end-of-iter barrier: next iteration's post-stage __syncthreads orders LDS reuse.
    *(unsigned int*)(void*)(ymidbC + (size_t)rowl * 512 + dg) = pack2bf(yv.x, yv.y);
  }
}

// ---------------------------------------------------------------- fused adapter + final residual (in-place on y2)
__global__ __launch_bounds__(256) void adapter_out_kernel(
    float* __restrict__ y2,              // [RCH_][512] in/out (lives in d_out)
    const __bf16* __restrict__ ymidb,    // [RCH_][512]
    const float* __restrict__ awT0f,     // [512][64] = aw0^T (f32)
    const float* __restrict__ awT1f,     // [64][512] = aw1^T (f32)
    const float* __restrict__ ab0, const float* __restrict__ ab1){
  __shared__ float zl[16 * 64];
  const int w = threadIdx.x >> 6, l = threadIdx.x & 63;
  const int r0 = blockIdx.x * 16;
  const float bz = ab0[l];
  #pragma unroll
  for (int rr = 0; rr < 4; ++rr) {
    int rowl = w*4 + rr;
    const float* yr = y2 + (size_t)(r0 + rowl) * 512;
    float acc = bz;
    #pragma unroll 4
    for (int k = 0; k < 512; k += 4) {
      float4 v = *(const float4*)(yr + k);
      acc += v.x*awT0f[(k+0)*64 + l] + v.y*awT0f[(k+1)*64 + l]
           + v.z*awT0f[(k+2)*64 + l] + v.w*awT0f[(k+3)*64 + l];
    }
    zl[rowl*64 + l] = fmaxf(acc, 0.f);
  }
  __syncthreads();
  #pragma unroll
  for (int rr = 0; rr < 4; ++rr) {
    int rowl = w*4 + rr; int row = r0 + rowl;
    const float* yr = y2  + (size_t)row * 512;
    const __bf16* mr = ymidb + (size_t)row * 512;
    #pragma unroll
    for (int dd = 0; dd < 8; ++dd) {
      int d = dd*64 + l;
      float acc = ab1[d] + yr[d] + (float)mr[d];
      #pragma unroll 4
      for (int j = 0; j < 64; ++j) acc += zl[rowl*64 + j] * awT1f[j*512 + d];
      y2[(size_t)row * 512 + d] = acc;
    }
  }
}

// ---------------------------------------------------------------- launch
extern "C" void kernel_launch(void* const* d_in, const int* in_sizes, int n_in,
                              void* d_out, int out_size, void* d_ws, size_t ws_size,
                              hipStream_t stream){
  (void)in_sizes; (void)n_in; (void)out_size; (void)ws_size;
  const float* x    = (const float*)d_in[0];
  const void*  first=               d_in[1];
  const float* h0   = (const float*)d_in[2];
  const float* c0   = (const float*)d_in[3];
  const float* ln_g = (const float*)d_in[4];
  const float* ln_b = (const float*)d_in[5];
  const float* Wih  = (const float*)d_in[6];
  const float* Whh  = (const float*)d_in[7];
  const float* bih  = (const float*)d_in[8];
  const float* bhh  = (const float*)d_in[9];
  const float* m0w  = (const float*)d_in[10];
  const float* m0b  = (const float*)d_in[11];
  const float* m1w  = (const float*)d_in[12];
  const float* m1b  = (const float*)d_in[13];
  const float* aw0  = (const float*)d_in[14];
  const float* ab0  = (const float*)d_in[15];
  const float* aw1  = (const float*)d_in[16];
  const float* ab1  = (const float*)d_in[17];

  // workspace layout — ~109.5 MB (< 126 MB proven available in r10/r11 Plan-A runs)
  char* ws = (char*)d_ws;
  __bf16* buf0  = (__bf16*)(ws + 0LL);             // 64 MB: preH, later a1 (disjoint lifetimes per half)
  __bf16* xnbfH = (__bf16*)(ws + 67108864LL);      // 16 MB
  __bf16* ymidbH= (__bf16*)(ws + 83886080LL);      // 16 MB
  __bf16* wihb  = (__bf16*)(ws + 100663296LL);     // 2 MB
  __bf16* whhb  = (__bf16*)(ws + 102760448LL);     // 2 MB
  __bf16* m0bf  = (__bf16*)(ws + 104857600LL);     // 2 MB
  __bf16* m1bf  = (__bf16*)(ws + 106954752LL);     // 2 MB
  float*  awT0f = (float*) (ws + 109051904LL);     // 128 KB
  float*  awT1f = (float*) (ws + 109182976LL);     // 128 KB
  unsigned long long* HP = (unsigned long long*)(ws + 109314048LL);  // 128 KB
  float*  cstate= (float*) (ws + 109445120LL);     // 64 KB
  unsigned int* mode = (unsigned int*)(ws + 109510656LL);
  __bf16* preH = buf0;
  __bf16* a1   = buf0;                             // alias (disjoint lifetime)

  float* out  = (float*)d_out;
  float* hout = out + (size_t)TB_ * D_;
  float* cout = hout + B_ * D_;

  hipMemsetAsync(HP, 0, 131072, stream);           // kill cross-replay stale tags
  detect_first_kernel<<<1, 256, 0, stream>>>((const unsigned char*)first, mode);
  convert_w_kernel<<<4352, 256, 0, stream>>>(Wih, Whh, m0w, m1w, aw0, aw1,
                                             wihb, whhb, m0bf, m1bf, awT0f, awT1f);
  for (int h = 0; h < 2; ++h) {
    const size_t ro = (size_t)h * RCH_;
    ln_kernel<<<RCH_/4, 256, 0, stream>>>(x + ro * D_, ln_g, ln_b, xnbfH);
    gemm_bt<0,1,1><<<dim3(RCH_/128, FF_/128), 256, 0, stream>>>(xnbfH, wihb, bih, bhh,
                                                                nullptr, preH, RCH_, 2048, 512);
    lstm_scan<<<16, 512, 0, stream>>>(whhb, preH, x, first, h0, c0, cstate, ymidbH,
                                      HP, mode, hout, cout, h * TCH_);
    gemm_bt<1,1,0><<<dim3(RCH_/128, FF_/128), 256, 0, stream>>>(ymidbH, m0bf, m0b, nullptr,
                                                                nullptr, a1, RCH_, FF_, 512);
    gemm_bt<0,0,0><<<dim3(RCH_/128, D_/128), 256, 0, stream>>>(a1, m1bf, m1b, nullptr,
                                                               out + ro * D_, nullptr, RCH_, D_, FF_);
    adapter_out_kernel<<<RCH_/16, 256, 0, stream>>>(out + ro * D_, ymidbH, awT0f, awT1f, ab0, ab1);
  }
}